// Round 3
// baseline (181.428 us; speedup 1.0000x reference)
//
#include <hip/hip_runtime.h>
#include <math.h>

constexpr int B_    = 32;
constexpr int In_   = 2048;
constexpr int Din_  = 8;
constexpr int N_    = 64;
constexpr int Dout_ = 16;
constexpr int C_    = 32;
constexpr int ICP   = 64;     // In_/C_
constexpr float EPS = 1e-7f;

__device__ __forceinline__ float rlane(float v, int l) {
    return __uint_as_float(__builtin_amdgcn_readlane(__float_as_uint(v), l));
}

// ---------------------------------------------------------------------------
// D1: blocks 0..31  -> v0[b] (iteration-0 output; softmax(0) uniform)
//     blocks 32..39 -> transpose W[n][c][d][k] -> Wt[c][d][n][k]; block 32
//                      also zeroes the 64 atomic counters.
// ---------------------------------------------------------------------------
__global__ __launch_bounds__(256) void caps_pre(
    const float* __restrict__ x, const float* __restrict__ W,
    const float* __restrict__ bias, float* __restrict__ v0,
    float* __restrict__ Wt, int* __restrict__ cnt)
{
    const int t = threadIdx.x;

    if (blockIdx.x >= 32) {
        if (blockIdx.x == 32 && t < 64) cnt[t] = 0;
        const int g = (blockIdx.x - 32) * 256 + t;
        #pragma unroll 4
        for (int q = 0; q < 128; ++q) {
            const int didx = g + q * 2048;            // dst flat: ((c*16+d)*64+n)*8+k
            const int k = didx & 7;
            const int n = (didx >> 3) & 63;
            const int d = (didx >> 9) & 15;
            const int c = didx >> 13;
            Wt[didx] = W[((n * 32 + c) * 16 + d) * 8 + k];
        }
        return;
    }

    const int b = blockIdx.x;
    __shared__ float xs[In_ * Din_];        // 64 KB
    __shared__ float xbar[C_][Din_];
    __shared__ float s0[N_][Dout_ + 1];
    __shared__ float scl[N_];

    const float4* xg = (const float4*)(x + (size_t)b * In_ * Din_);
    #pragma unroll
    for (int q = 0; q < 16; ++q) ((float4*)xs)[t + 256 * q] = xg[t + 256 * q];
    __syncthreads();

    {
        const int c = t >> 3, k = t & 7;
        float acc = 0.f;
        #pragma unroll
        for (int ii = 0; ii < ICP; ++ii) {
            const int i = (ii + c) & 63;
            acc += xs[(c * ICP + i) * Din_ + k];
        }
        xbar[c][k] = acc * (1.f / 64.f);
    }
    __syncthreads();

    {
        float acc[4]; int nn[4], dd[4];
        #pragma unroll
        for (int q = 0; q < 4; ++q) {
            const int it = t + 256 * q;
            nn[q] = it >> 4; dd[q] = it & 15;
            acc[q] = bias[nn[q] * Dout_ + dd[q]];
        }
        for (int c = 0; c < C_; ++c) {
            float xb[8];
            #pragma unroll
            for (int k = 0; k < 8; ++k) xb[k] = xbar[c][k];
            #pragma unroll
            for (int q = 0; q < 4; ++q) {
                const float4* wp = (const float4*)(W + ((nn[q] * C_ + c) * Dout_ + dd[q]) * Din_);
                const float4 w0 = wp[0], w1 = wp[1];
                acc[q] += w0.x * xb[0] + w0.y * xb[1] + w0.z * xb[2] + w0.w * xb[3]
                        + w1.x * xb[4] + w1.y * xb[5] + w1.z * xb[6] + w1.w * xb[7];
            }
        }
        #pragma unroll
        for (int q = 0; q < 4; ++q) s0[nn[q]][dd[q]] = acc[q];
    }
    __syncthreads();

    if (t < N_) {
        float sn = 0.f;
        #pragma unroll
        for (int d = 0; d < Dout_; ++d) sn += s0[t][d] * s0[t][d];
        scl[t] = sn / (1.f + sn) / sqrtf(sn + EPS);
    }
    __syncthreads();

    {
        const int n = t >> 2, d0 = (t & 3) * 4;
        const float sc = scl[n];
        float4 o;
        o.x = s0[n][d0 + 0] * sc; o.y = s0[n][d0 + 1] * sc;
        o.z = s0[n][d0 + 2] * sc; o.w = s0[n][d0 + 3] * sc;
        ((float4*)(v0 + (size_t)b * N_ * Dout_))[t] = o;
    }
}

// ---------------------------------------------------------------------------
// Routing iteration: ONE WAVE per (b,c). lane = input capsule i for
// logits/softmax, lane = output capsule n for U/y/s stages. Cross-lane
// broadcasts via v_readlane; single conflict-free LDS transpose for the
// routing weights. Last block per b (atomic counter) reduces s over c,
// adds bias, squashes -> dst (v1 for iter1, final out for iter2).
// ---------------------------------------------------------------------------
__global__ __launch_bounds__(64) void caps_route(
    const float* __restrict__ x, const float* __restrict__ Wt,
    const float* __restrict__ bias, const float* __restrict__ v_in,
    float* __restrict__ U_g, float* __restrict__ s_out,
    float* __restrict__ dst, int* __restrict__ cnt, int accumulate)
{
    const int b = blockIdx.x >> 5;
    const int c = blockIdx.x & 31;
    const int lane = threadIdx.x;

    __shared__ float lgT[N_][ICP + 1];   // lgT[n][i] = cw[i][n]; 16.25 KB

    // ---- v for this lane's n (= lane)
    float v[16];
    {
        const float4* vp = (const float4*)(v_in + ((size_t)b * 64 + lane) * 16);
        #pragma unroll
        for (int q = 0; q < 4; ++q) {
            const float4 a = vp[q];
            v[q * 4 + 0] = a.x; v[q * 4 + 1] = a.y; v[q * 4 + 2] = a.z; v[q * 4 + 3] = a.w;
        }
    }

    // ---- U[n=lane][k] = sum_d v[n][d] * W[n][c][d][k]   (coalesced Wt reads)
    float U[8] = {0, 0, 0, 0, 0, 0, 0, 0};
    const float4* wt = (const float4*)Wt + ((size_t)c * 1024 + lane) * 2;
    #pragma unroll
    for (int d = 0; d < 16; ++d) {
        const float4 w0 = wt[d * 128], w1 = wt[d * 128 + 1];
        const float vd = v[d];
        U[0] += vd * w0.x; U[1] += vd * w0.y; U[2] += vd * w0.z; U[3] += vd * w0.w;
        U[4] += vd * w1.x; U[5] += vd * w1.y; U[6] += vd * w1.z; U[7] += vd * w1.w;
    }
    {
        float4* up = (float4*)(U_g + (((size_t)b * 32 + c) * 64 + lane) * 8);
        if (accumulate) {
            const float4 u0 = up[0], u1 = up[1];
            U[0] += u0.x; U[1] += u0.y; U[2] += u0.z; U[3] += u0.w;
            U[4] += u1.x; U[5] += u1.y; U[6] += u1.z; U[7] += u1.w;
        } else {
            float4 u0, u1;
            u0.x = U[0]; u0.y = U[1]; u0.z = U[2]; u0.w = U[3];
            u1.x = U[4]; u1.y = U[5]; u1.z = U[6]; u1.w = U[7];
            up[0] = u0; up[1] = u1;
        }
    }

    // ---- x for this lane's i (= lane)
    float xr[8];
    {
        const float4* xp = (const float4*)(x + ((size_t)b * In_ + c * ICP + lane) * 8);
        const float4 x0 = xp[0], x1 = xp[1];
        xr[0] = x0.x; xr[1] = x0.y; xr[2] = x0.z; xr[3] = x0.w;
        xr[4] = x1.x; xr[5] = x1.y; xr[6] = x1.z; xr[7] = x1.w;
    }

    // ---- logits: acc[n] = U[n][:] . x[i=lane][:]  (U broadcast via readlane)
    float acc[64];
    #pragma unroll
    for (int n = 0; n < 64; ++n) {
        float a;
        a  = rlane(U[0], n) * xr[0];
        a += rlane(U[1], n) * xr[1];
        a += rlane(U[2], n) * xr[2];
        a += rlane(U[3], n) * xr[3];
        a += rlane(U[4], n) * xr[4];
        a += rlane(U[5], n) * xr[5];
        a += rlane(U[6], n) * xr[6];
        a += rlane(U[7], n) * xr[7];
        acc[n] = a;
    }

    // ---- softmax over n: pure per-lane VALU
    float m = acc[0];
    #pragma unroll
    for (int n = 1; n < 64; ++n) m = fmaxf(m, acc[n]);
    float ssum = 0.f;
    #pragma unroll
    for (int n = 0; n < 64; ++n) { acc[n] = expf(acc[n] - m); ssum += acc[n]; }
    const float inv = 1.f / ssum;

    // ---- transpose via LDS (conflict-free: bank = (n+lane)%32, 2-way)
    #pragma unroll
    for (int n = 0; n < 64; ++n) lgT[n][lane] = acc[n] * inv;

    // ---- y[n=lane][k] = sum_i cw[i][n] * x[i][k]
    float y[8] = {0, 0, 0, 0, 0, 0, 0, 0};
    #pragma unroll
    for (int i = 0; i < 64; ++i) {
        const float cw = lgT[lane][i];
        y[0] += cw * rlane(xr[0], i);
        y[1] += cw * rlane(xr[1], i);
        y[2] += cw * rlane(xr[2], i);
        y[3] += cw * rlane(xr[3], i);
        y[4] += cw * rlane(xr[4], i);
        y[5] += cw * rlane(xr[5], i);
        y[6] += cw * rlane(xr[6], i);
        y[7] += cw * rlane(xr[7], i);
    }

    // ---- s_out[b][c][n=lane][d] = sum_k W[n][c][d][k] * y[n][k]
    {
        float4* sp = (float4*)(s_out + (((size_t)b * 32 + c) * 64 + lane) * 16);
        #pragma unroll
        for (int dq = 0; dq < 4; ++dq) {
            float4 o;
            float* op = (float*)&o;
            #pragma unroll
            for (int j = 0; j < 4; ++j) {
                const int d = dq * 4 + j;
                const float4 w0 = wt[d * 128], w1 = wt[d * 128 + 1];
                op[j] = w0.x * y[0] + w0.y * y[1] + w0.z * y[2] + w0.w * y[3]
                      + w1.x * y[4] + w1.y * y[5] + w1.z * y[6] + w1.w * y[7];
            }
            sp[dq] = o;
        }
    }

    // ---- last block per b finalizes: reduce over c + bias + squash -> dst
    __threadfence();
    int old = 0;
    if (lane == 0) old = atomicAdd(cnt + b, 1);
    old = __shfl(old, 0);
    if (old == 31) {
        __threadfence();
        float s[16];
        {
            const float4* bp = (const float4*)(bias + lane * 16);
            #pragma unroll
            for (int q = 0; q < 4; ++q) {
                const float4 a = bp[q];
                s[q * 4 + 0] = a.x; s[q * 4 + 1] = a.y; s[q * 4 + 2] = a.z; s[q * 4 + 3] = a.w;
            }
        }
        for (int cc = 0; cc < 32; ++cc) {
            const float4* pp = (const float4*)(s_out + (((size_t)b * 32 + cc) * 64 + lane) * 16);
            #pragma unroll
            for (int q = 0; q < 4; ++q) {
                const float4 a = pp[q];
                s[q * 4 + 0] += a.x; s[q * 4 + 1] += a.y; s[q * 4 + 2] += a.z; s[q * 4 + 3] += a.w;
            }
        }
        float sn = 0.f;
        #pragma unroll
        for (int d = 0; d < 16; ++d) sn += s[d] * s[d];
        const float scale = sn / (1.f + sn) / sqrtf(sn + EPS);
        float4* op = (float4*)(dst + ((size_t)b * 64 + lane) * 16);
        #pragma unroll
        for (int q = 0; q < 4; ++q) {
            float4 o;
            o.x = s[q * 4 + 0] * scale; o.y = s[q * 4 + 1] * scale;
            o.z = s[q * 4 + 2] * scale; o.w = s[q * 4 + 3] * scale;
            op[q] = o;
        }
    }
}

extern "C" void kernel_launch(void* const* d_in, const int* in_sizes, int n_in,
                              void* d_out, int out_size, void* d_ws, size_t ws_size,
                              hipStream_t stream) {
    const float* x    = (const float*)d_in[0];   // [B, In, Din]
    const float* W    = (const float*)d_in[1];   // [N, C, Dout, Din]
    const float* bias = (const float*)d_in[2];   // [N, Dout]
    float* out = (float*)d_out;                  // [B, N, Dout]

    float* ws     = (float*)d_ws;
    float* Wt     = ws;                                        // 262,144 f
    float* s_part = Wt     + (size_t)C_ * Dout_ * N_ * Din_;   // 1,048,576 f
    float* U_g    = s_part + (size_t)B_ * C_ * N_ * Dout_;     //   524,288 f
    float* v0     = U_g    + (size_t)B_ * C_ * N_ * Din_;      //    32,768 f
    float* v1     = v0     + (size_t)B_ * N_ * Dout_;          //    32,768 f
    int*   cnt    = (int*)(v1 + (size_t)B_ * N_ * Dout_);      //        64 i

    caps_pre  <<<40,       256, 0, stream>>>(x, W, bias, v0, Wt, cnt);
    caps_route<<<B_ * C_,   64, 0, stream>>>(x, Wt, bias, v0, U_g, s_part, v1,  cnt,      0);
    caps_route<<<B_ * C_,   64, 0, stream>>>(x, Wt, bias, v1, U_g, s_part, out, cnt + 32, 1);
}

// Round 4
// 177.509 us; speedup vs baseline: 1.0221x; 1.0221x over previous
//
#include <hip/hip_runtime.h>
#include <math.h>

constexpr int B_    = 32;
constexpr int In_   = 2048;
constexpr int Din_  = 8;
constexpr int N_    = 64;
constexpr int Dout_ = 16;
constexpr int C_    = 32;
constexpr int ICP   = 64;     // In_/C_
constexpr float EPS = 1e-7f;

__device__ __forceinline__ float rlane(float v, int l) {
    return __uint_as_float(__builtin_amdgcn_readlane(__float_as_uint(v), l));
}

// ---------------------------------------------------------------------------
// D1: blocks 0..31  -> v0[b] (iteration-0 output; softmax(0) uniform)
//     blocks 32..39 -> transpose W[n][c][d][k] -> Wt[c][d][n][k]; block 32
//                      also zeroes the 64 atomic counters.
// ---------------------------------------------------------------------------
__global__ __launch_bounds__(256) void caps_pre(
    const float* __restrict__ x, const float* __restrict__ W,
    const float* __restrict__ bias, float* __restrict__ v0,
    float* __restrict__ Wt, int* __restrict__ cnt)
{
    const int t = threadIdx.x;

    if (blockIdx.x >= 32) {
        if (blockIdx.x == 32 && t < 64) cnt[t] = 0;
        const int g = (blockIdx.x - 32) * 256 + t;
        #pragma unroll 4
        for (int q = 0; q < 128; ++q) {
            const int didx = g + q * 2048;            // dst flat: ((c*16+d)*64+n)*8+k
            const int k = didx & 7;
            const int n = (didx >> 3) & 63;
            const int d = (didx >> 9) & 15;
            const int c = didx >> 13;
            Wt[didx] = W[((n * 32 + c) * 16 + d) * 8 + k];
        }
        return;
    }

    const int b = blockIdx.x;
    __shared__ float xs[In_ * Din_];        // 64 KB
    __shared__ float xbar[C_][Din_];
    __shared__ float s0[N_][Dout_ + 1];
    __shared__ float scl[N_];

    const float4* xg = (const float4*)(x + (size_t)b * In_ * Din_);
    #pragma unroll
    for (int q = 0; q < 16; ++q) ((float4*)xs)[t + 256 * q] = xg[t + 256 * q];
    __syncthreads();

    {
        const int c = t >> 3, k = t & 7;
        float acc = 0.f;
        #pragma unroll
        for (int ii = 0; ii < ICP; ++ii) {
            const int i = (ii + c) & 63;
            acc += xs[(c * ICP + i) * Din_ + k];
        }
        xbar[c][k] = acc * (1.f / 64.f);
    }
    __syncthreads();

    {
        float acc[4]; int nn[4], dd[4];
        #pragma unroll
        for (int q = 0; q < 4; ++q) {
            const int it = t + 256 * q;
            nn[q] = it >> 4; dd[q] = it & 15;
            acc[q] = bias[nn[q] * Dout_ + dd[q]];
        }
        for (int c = 0; c < C_; ++c) {
            float xb[8];
            #pragma unroll
            for (int k = 0; k < 8; ++k) xb[k] = xbar[c][k];
            #pragma unroll
            for (int q = 0; q < 4; ++q) {
                const float4* wp = (const float4*)(W + ((nn[q] * C_ + c) * Dout_ + dd[q]) * Din_);
                const float4 w0 = wp[0], w1 = wp[1];
                acc[q] += w0.x * xb[0] + w0.y * xb[1] + w0.z * xb[2] + w0.w * xb[3]
                        + w1.x * xb[4] + w1.y * xb[5] + w1.z * xb[6] + w1.w * xb[7];
            }
        }
        #pragma unroll
        for (int q = 0; q < 4; ++q) s0[nn[q]][dd[q]] = acc[q];
    }
    __syncthreads();

    if (t < N_) {
        float sn = 0.f;
        #pragma unroll
        for (int d = 0; d < Dout_; ++d) sn += s0[t][d] * s0[t][d];
        scl[t] = sn / (1.f + sn) / sqrtf(sn + EPS);
    }
    __syncthreads();

    {
        const int n = t >> 2, d0 = (t & 3) * 4;
        const float sc = scl[n];
        float4 o;
        o.x = s0[n][d0 + 0] * sc; o.y = s0[n][d0 + 1] * sc;
        o.z = s0[n][d0 + 2] * sc; o.w = s0[n][d0 + 3] * sc;
        ((float4*)(v0 + (size_t)b * N_ * Dout_))[t] = o;
    }
}

// ---------------------------------------------------------------------------
// Routing iteration: ONE WAVE per (b,c); lane = i for logits, lane = n for
// U/y/s. No register logit array: exp fused into logit loop (no max-sub —
// logits bounded, identical after normalization), 1/sum folded into xr.
// Only LDS: padded 64x65 exp tile (2-way aliasing = free).
// ---------------------------------------------------------------------------
__global__ __launch_bounds__(64) void caps_route(
    const float* __restrict__ x, const float* __restrict__ Wt,
    const float* __restrict__ bias, const float* __restrict__ v_in,
    float* __restrict__ U_g, float* __restrict__ s_out,
    float* __restrict__ dst, int* __restrict__ cnt, int accumulate)
{
    const int b = blockIdx.x >> 5;
    const int c = blockIdx.x & 31;
    const int lane = threadIdx.x;

    __shared__ float lg[N_][ICP + 1];   // lg[i][n] = exp(logit); 16.25 KB

    const float4* wt = (const float4*)Wt + ((size_t)c * 1024 + lane) * 2;

    // ---- v for this lane's n (= lane)
    float v[16];
    {
        const float4* vp = (const float4*)(v_in + ((size_t)b * 64 + lane) * 16);
        #pragma unroll
        for (int q = 0; q < 4; ++q) {
            const float4 a = vp[q];
            v[q * 4 + 0] = a.x; v[q * 4 + 1] = a.y; v[q * 4 + 2] = a.z; v[q * 4 + 3] = a.w;
        }
    }

    // ---- U[n=lane][k] = sum_d v[n][d] * W[n][c][d][k]
    float U[8] = {0, 0, 0, 0, 0, 0, 0, 0};
    #pragma unroll
    for (int d = 0; d < 16; ++d) {
        const float4 w0 = wt[d * 128], w1 = wt[d * 128 + 1];
        const float vd = v[d];
        U[0] += vd * w0.x; U[1] += vd * w0.y; U[2] += vd * w0.z; U[3] += vd * w0.w;
        U[4] += vd * w1.x; U[5] += vd * w1.y; U[6] += vd * w1.z; U[7] += vd * w1.w;
    }
    {
        float4* up = (float4*)(U_g + (((size_t)b * 32 + c) * 64 + lane) * 8);
        if (accumulate) {
            const float4 u0 = up[0], u1 = up[1];
            U[0] += u0.x; U[1] += u0.y; U[2] += u0.z; U[3] += u0.w;
            U[4] += u1.x; U[5] += u1.y; U[6] += u1.z; U[7] += u1.w;
        } else {
            float4 u0, u1;
            u0.x = U[0]; u0.y = U[1]; u0.z = U[2]; u0.w = U[3];
            u1.x = U[4]; u1.y = U[5]; u1.z = U[6]; u1.w = U[7];
            up[0] = u0; up[1] = u1;
        }
    }

    // ---- x for this lane's i (= lane)
    float xr[8];
    {
        const float4* xp = (const float4*)(x + ((size_t)b * In_ + c * ICP + lane) * 8);
        const float4 x0 = xp[0], x1 = xp[1];
        xr[0] = x0.x; xr[1] = x0.y; xr[2] = x0.z; xr[3] = x0.w;
        xr[4] = x1.x; xr[5] = x1.y; xr[6] = x1.z; xr[7] = x1.w;
    }

    // ---- logits + exp + running sum (no register array, no max pass)
    float ssum = 0.f;
    #pragma unroll
    for (int n = 0; n < 64; ++n) {
        float a;
        a  = rlane(U[0], n) * xr[0];
        a += rlane(U[1], n) * xr[1];
        a += rlane(U[2], n) * xr[2];
        a += rlane(U[3], n) * xr[3];
        a += rlane(U[4], n) * xr[4];
        a += rlane(U[5], n) * xr[5];
        a += rlane(U[6], n) * xr[6];
        a += rlane(U[7], n) * xr[7];
        const float e = __expf(a);
        ssum += e;
        lg[lane][n] = e;
    }
    // fold softmax normalization into this lane's x fragment
    {
        const float inv = 1.f / ssum;
        #pragma unroll
        for (int k = 0; k < 8; ++k) xr[k] *= inv;
    }
    __syncthreads();   // single wave: cheap; orders LDS writes vs cross-row reads

    // ---- y[n=lane][k] = sum_i e[i][n]/ssum_i * x[i][k]
    float y[8] = {0, 0, 0, 0, 0, 0, 0, 0};
    #pragma unroll
    for (int i = 0; i < 64; ++i) {
        const float cw = lg[i][lane];
        y[0] += cw * rlane(xr[0], i);
        y[1] += cw * rlane(xr[1], i);
        y[2] += cw * rlane(xr[2], i);
        y[3] += cw * rlane(xr[3], i);
        y[4] += cw * rlane(xr[4], i);
        y[5] += cw * rlane(xr[5], i);
        y[6] += cw * rlane(xr[6], i);
        y[7] += cw * rlane(xr[7], i);
    }

    // ---- s_out[b][c][n=lane][d] = sum_k W[n][c][d][k] * y[n][k]
    {
        float4* sp = (float4*)(s_out + (((size_t)b * 32 + c) * 64 + lane) * 16);
        #pragma unroll
        for (int dq = 0; dq < 4; ++dq) {
            float4 o;
            float* op = (float*)&o;
            #pragma unroll
            for (int j = 0; j < 4; ++j) {
                const int d = dq * 4 + j;
                const float4 w0 = wt[d * 128], w1 = wt[d * 128 + 1];
                op[j] = w0.x * y[0] + w0.y * y[1] + w0.z * y[2] + w0.w * y[3]
                      + w1.x * y[4] + w1.y * y[5] + w1.z * y[6] + w1.w * y[7];
            }
            sp[dq] = o;
        }
    }

    // ---- last block per b finalizes: reduce over c + bias + squash -> dst
    __threadfence();
    int old = 0;
    if (lane == 0) old = atomicAdd(cnt + b, 1);
    old = __shfl(old, 0);
    if (old == 31) {
        __threadfence();
        float s[16];
        {
            const float4* bp = (const float4*)(bias + lane * 16);
            #pragma unroll
            for (int q = 0; q < 4; ++q) {
                const float4 a = bp[q];
                s[q * 4 + 0] = a.x; s[q * 4 + 1] = a.y; s[q * 4 + 2] = a.z; s[q * 4 + 3] = a.w;
            }
        }
        for (int cc = 0; cc < 32; ++cc) {
            const float4* pp = (const float4*)(s_out + (((size_t)b * 32 + cc) * 64 + lane) * 16);
            #pragma unroll
            for (int q = 0; q < 4; ++q) {
                const float4 a = pp[q];
                s[q * 4 + 0] += a.x; s[q * 4 + 1] += a.y; s[q * 4 + 2] += a.z; s[q * 4 + 3] += a.w;
            }
        }
        float sn = 0.f;
        #pragma unroll
        for (int d = 0; d < 16; ++d) sn += s[d] * s[d];
        const float scale = sn / (1.f + sn) / sqrtf(sn + EPS);
        float4* op = (float4*)(dst + ((size_t)b * 64 + lane) * 16);
        #pragma unroll
        for (int q = 0; q < 4; ++q) {
            float4 o;
            o.x = s[q * 4 + 0] * scale; o.y = s[q * 4 + 1] * scale;
            o.z = s[q * 4 + 2] * scale; o.w = s[q * 4 + 3] * scale;
            op[q] = o;
        }
    }
}

extern "C" void kernel_launch(void* const* d_in, const int* in_sizes, int n_in,
                              void* d_out, int out_size, void* d_ws, size_t ws_size,
                              hipStream_t stream) {
    const float* x    = (const float*)d_in[0];   // [B, In, Din]
    const float* W    = (const float*)d_in[1];   // [N, C, Dout, Din]
    const float* bias = (const float*)d_in[2];   // [N, Dout]
    float* out = (float*)d_out;                  // [B, N, Dout]

    float* ws     = (float*)d_ws;
    float* Wt     = ws;                                        // 262,144 f
    float* s_part = Wt     + (size_t)C_ * Dout_ * N_ * Din_;   // 1,048,576 f
    float* U_g    = s_part + (size_t)B_ * C_ * N_ * Dout_;     //   524,288 f
    float* v0     = U_g    + (size_t)B_ * C_ * N_ * Din_;      //    32,768 f
    float* v1     = v0     + (size_t)B_ * N_ * Dout_;          //    32,768 f
    int*   cnt    = (int*)(v1 + (size_t)B_ * N_ * Dout_);      //        64 i

    caps_pre  <<<40,       256, 0, stream>>>(x, W, bias, v0, Wt, cnt);
    caps_route<<<B_ * C_,   64, 0, stream>>>(x, Wt, bias, v0, U_g, s_part, v1,  cnt,      0);
    caps_route<<<B_ * C_,   64, 0, stream>>>(x, Wt, bias, v1, U_g, s_part, out, cnt + 32, 1);
}

// Round 5
// 108.162 us; speedup vs baseline: 1.6774x; 1.6411x over previous
//
#include <hip/hip_runtime.h>
#include <math.h>

constexpr int B_    = 32;
constexpr int In_   = 2048;
constexpr int Din_  = 8;
constexpr int N_    = 64;
constexpr int Dout_ = 16;
constexpr int C_    = 32;
constexpr int ICP   = 64;     // In_/C_
constexpr float EPS = 1e-7f;

// ---------------------------------------------------------------------------
// K1: iteration 0 (softmax(0) uniform -> channel means). One block per b.
// ---------------------------------------------------------------------------
__global__ __launch_bounds__(256) void caps_pre(
    const float* __restrict__ x, const float* __restrict__ W,
    const float* __restrict__ bias, float* __restrict__ v0)
{
    const int b = blockIdx.x, t = threadIdx.x;

    __shared__ float xs[In_ * Din_];        // 64 KB
    __shared__ float xbar[C_][Din_];
    __shared__ float s0[N_][Dout_ + 1];
    __shared__ float scl[N_];

    const float4* xg = (const float4*)(x + (size_t)b * In_ * Din_);
    #pragma unroll
    for (int q = 0; q < 16; ++q) ((float4*)xs)[t + 256 * q] = xg[t + 256 * q];
    __syncthreads();

    {
        const int c = t >> 3, k = t & 7;
        float acc = 0.f;
        #pragma unroll
        for (int ii = 0; ii < ICP; ++ii) {
            const int i = (ii + c) & 63;
            acc += xs[(c * ICP + i) * Din_ + k];
        }
        xbar[c][k] = acc * (1.f / 64.f);
    }
    __syncthreads();

    {
        float acc[4]; int nn[4], dd[4];
        #pragma unroll
        for (int q = 0; q < 4; ++q) {
            const int it = t + 256 * q;
            nn[q] = it >> 4; dd[q] = it & 15;
            acc[q] = bias[nn[q] * Dout_ + dd[q]];
        }
        for (int c = 0; c < C_; ++c) {
            float xb[8];
            #pragma unroll
            for (int k = 0; k < 8; ++k) xb[k] = xbar[c][k];
            #pragma unroll
            for (int q = 0; q < 4; ++q) {
                const float4* wp = (const float4*)(W + ((nn[q] * C_ + c) * Dout_ + dd[q]) * Din_);
                const float4 w0 = wp[0], w1 = wp[1];
                acc[q] += w0.x * xb[0] + w0.y * xb[1] + w0.z * xb[2] + w0.w * xb[3]
                        + w1.x * xb[4] + w1.y * xb[5] + w1.z * xb[6] + w1.w * xb[7];
            }
        }
        #pragma unroll
        for (int q = 0; q < 4; ++q) s0[nn[q]][dd[q]] = acc[q];
    }
    __syncthreads();

    if (t < N_) {
        float sn = 0.f;
        #pragma unroll
        for (int d = 0; d < Dout_; ++d) sn += s0[t][d] * s0[t][d];
        scl[t] = sn / (1.f + sn) / sqrtf(sn + EPS);
    }
    __syncthreads();

    {
        const int n = t >> 2, d0 = (t & 3) * 4;
        const float sc = scl[n];
        float4 o;
        o.x = s0[n][d0 + 0] * sc; o.y = s0[n][d0 + 1] * sc;
        o.z = s0[n][d0 + 2] * sc; o.w = s0[n][d0 + 3] * sc;
        ((float4*)(v0 + (size_t)b * N_ * Dout_))[t] = o;
    }
}

// ---------------------------------------------------------------------------
// Routing iteration: 256 threads per (b,c), all stages wave-distributed,
// zero readlanes, conflict-free/broadcast LDS only.
// ---------------------------------------------------------------------------
__global__ __launch_bounds__(256) void caps_route(
    const float* __restrict__ x, const float* __restrict__ W,
    const float* __restrict__ bias, const float* __restrict__ v_src,
    const float* __restrict__ s_src, float* __restrict__ U_g,
    float* __restrict__ s_out, int accumulate)
{
    const int b = blockIdx.x >> 5;
    const int c = blockIdx.x & 31;
    const int t = threadIdx.x;
    const int w = t >> 6, l = t & 63;
    const int n4 = t >> 2, q4 = t & 3;     // (n, quarter) role

    __shared__ float vs[N_][20];           // 5 KB   (20: float4-aligned rows)
    __shared__ float Us[N_][8];            // 2 KB
    __shared__ float xs[ICP][8];           // 2 KB
    __shared__ float lg[ICP][68];          // 17 KB  (68: b128-aligned, bank-skewed)
    __shared__ float ps[4][ICP];           // 1 KB
    __shared__ float inv_s[ICP];
    __shared__ float ys[4][N_][8];         // 8 KB

    // ---- prologue: vs[n][d] = v (iter1: read v0; iter2: reduce s_src+bias+squash)
    {
        float4 a;
        if (s_src) {
            a = *(const float4*)(bias + n4 * 16 + q4 * 4);
            for (int cc = 0; cc < 32; ++cc) {
                const float4 p = *(const float4*)(s_src + (((size_t)b * 32 + cc) * 64 + n4) * 16 + q4 * 4);
                a.x += p.x; a.y += p.y; a.z += p.z; a.w += p.w;
            }
            float sn = a.x * a.x + a.y * a.y + a.z * a.z + a.w * a.w;
            sn += __shfl_xor(sn, 1);
            sn += __shfl_xor(sn, 2);
            const float sc = sn / (1.f + sn) / sqrtf(sn + EPS);
            a.x *= sc; a.y *= sc; a.z *= sc; a.w *= sc;
        } else {
            a = *(const float4*)(v_src + ((size_t)b * 64 + n4) * 16 + q4 * 4);
        }
        *(float4*)&vs[n4][q4 * 4] = a;
    }
    __syncthreads();

    // ---- U stage: thread (n4,q4) covers d in [4q4,4q4+4); quad-shfl -> k pair
    {
        float pU[8] = {0, 0, 0, 0, 0, 0, 0, 0};
        #pragma unroll
        for (int dd = 0; dd < 4; ++dd) {
            const int d = q4 * 4 + dd;
            const float4* wp = (const float4*)(W + (((size_t)n4 * 32 + c) * 16 + d) * 8);
            const float4 w0 = wp[0], w1 = wp[1];
            const float vd = vs[n4][d];
            pU[0] += vd * w0.x; pU[1] += vd * w0.y; pU[2] += vd * w0.z; pU[3] += vd * w0.w;
            pU[4] += vd * w1.x; pU[5] += vd * w1.y; pU[6] += vd * w1.z; pU[7] += vd * w1.w;
        }
        #pragma unroll
        for (int k = 0; k < 8; ++k) {
            pU[k] += __shfl_xor(pU[k], 1);
            pU[k] += __shfl_xor(pU[k], 2);
        }
        float2 u2;
        u2.x = pU[2 * q4]; u2.y = pU[2 * q4 + 1];
        float2* ug = (float2*)(U_g + (((size_t)b * 32 + c) * 64 + n4) * 8 + 2 * q4);
        if (accumulate) {                  // iter2: read iter1's U, add; no store needed
            const float2 o = *ug;
            u2.x += o.x; u2.y += o.y;
        } else {                           // iter1: store for iter2
            *ug = u2;
        }
        *(float2*)&Us[n4][2 * q4] = u2;
    }

    // ---- x fragment for lane's capsule i = l (all waves); wave 0 mirrors to LDS
    float xr[8];
    {
        const float4* xp = (const float4*)(x + ((size_t)b * In_ + c * ICP + l) * 8);
        const float4 x0 = xp[0], x1 = xp[1];
        xr[0] = x0.x; xr[1] = x0.y; xr[2] = x0.z; xr[3] = x0.w;
        xr[4] = x1.x; xr[5] = x1.y; xr[6] = x1.z; xr[7] = x1.w;
        if (w == 0) {
            *(float4*)&xs[l][0] = x0;
            *(float4*)&xs[l][4] = x1;
        }
    }
    __syncthreads();

    // ---- logits+exp: wave w covers n in [16w,16w+16); lane = i; Us uniform-bcast
    {
        float e[16];
        float ssum = 0.f;
        #pragma unroll
        for (int nn = 0; nn < 16; ++nn) {
            const int n = w * 16 + nn;
            const float4 u0 = *(const float4*)&Us[n][0];
            const float4 u1 = *(const float4*)&Us[n][4];
            float a = u0.x * xr[0] + u0.y * xr[1] + u0.z * xr[2] + u0.w * xr[3]
                    + u1.x * xr[4] + u1.y * xr[5] + u1.z * xr[6] + u1.w * xr[7];
            const float ee = __expf(a);    // no max-pass: logits bounded (validated R3/R4)
            e[nn] = ee; ssum += ee;
        }
        #pragma unroll
        for (int qq = 0; qq < 4; ++qq) {
            float4 o;
            o.x = e[qq * 4 + 0]; o.y = e[qq * 4 + 1]; o.z = e[qq * 4 + 2]; o.w = e[qq * 4 + 3];
            *(float4*)&lg[l][w * 16 + qq * 4] = o;
        }
        ps[w][l] = ssum;
    }
    __syncthreads();

    if (t < 64) inv_s[t] = 1.f / (ps[0][t] + ps[1][t] + ps[2][t] + ps[3][t]);
    __syncthreads();

    // ---- y stage: wave w covers i in [16w,16w+16); lane = (nq=l>>2, kq=l&3)
    {
        const int nq = l >> 2, kq = l & 3;
        float y[8] = {0, 0, 0, 0, 0, 0, 0, 0};   // [4 n][2 k]
        #pragma unroll
        for (int ii = 0; ii < 16; ++ii) {
            const int i = w * 16 + ii;
            const float4 cw = *(const float4*)&lg[i][nq * 4];
            const float iv = inv_s[i];
            const float2 x2 = *(const float2*)&xs[i][kq * 2];
            const float c0 = cw.x * iv, c1 = cw.y * iv, c2 = cw.z * iv, c3 = cw.w * iv;
            y[0] += c0 * x2.x; y[1] += c0 * x2.y;
            y[2] += c1 * x2.x; y[3] += c1 * x2.y;
            y[4] += c2 * x2.x; y[5] += c2 * x2.y;
            y[6] += c3 * x2.x; y[7] += c3 * x2.y;
        }
        #pragma unroll
        for (int j = 0; j < 4; ++j) {
            float2 o; o.x = y[2 * j]; o.y = y[2 * j + 1];
            *(float2*)&ys[w][nq * 4 + j][kq * 2] = o;
        }
    }
    __syncthreads();

    // ---- s stage: thread (n4,q4): s_out[b][c][n][4q4..] = W[n,c,d,:] . y[n,:]
    {
        float yn[8];
        #pragma unroll
        for (int k = 0; k < 8; ++k)
            yn[k] = ys[0][n4][k] + ys[1][n4][k] + ys[2][n4][k] + ys[3][n4][k];
        float4 o;
        float* op = (float*)&o;
        #pragma unroll
        for (int dd = 0; dd < 4; ++dd) {
            const int d = q4 * 4 + dd;
            const float4* wp = (const float4*)(W + (((size_t)n4 * 32 + c) * 16 + d) * 8);
            const float4 w0 = wp[0], w1 = wp[1];
            op[dd] = w0.x * yn[0] + w0.y * yn[1] + w0.z * yn[2] + w0.w * yn[3]
                   + w1.x * yn[4] + w1.y * yn[5] + w1.z * yn[6] + w1.w * yn[7];
        }
        *(float4*)(s_out + (((size_t)b * 32 + c) * 64 + n4) * 16 + q4 * 4) = o;
    }
}

// ---------------------------------------------------------------------------
// K4: reduce s over c + bias + squash -> out. One block per b.
// ---------------------------------------------------------------------------
__global__ __launch_bounds__(256) void caps_out(
    const float* __restrict__ s_src, const float* __restrict__ bias,
    float* __restrict__ out)
{
    const int b = blockIdx.x, t = threadIdx.x;
    const int n = t >> 2, q = t & 3;

    float4 a = *(const float4*)(bias + n * 16 + q * 4);
    for (int cc = 0; cc < 32; ++cc) {
        const float4 p = *(const float4*)(s_src + (((size_t)b * 32 + cc) * 64 + n) * 16 + q * 4);
        a.x += p.x; a.y += p.y; a.z += p.z; a.w += p.w;
    }
    float sn = a.x * a.x + a.y * a.y + a.z * a.z + a.w * a.w;
    sn += __shfl_xor(sn, 1);
    sn += __shfl_xor(sn, 2);
    const float sc = sn / (1.f + sn) / sqrtf(sn + EPS);
    float4 o;
    o.x = a.x * sc; o.y = a.y * sc; o.z = a.z * sc; o.w = a.w * sc;
    *(float4*)(out + (size_t)b * 1024 + t * 4) = o;
}

extern "C" void kernel_launch(void* const* d_in, const int* in_sizes, int n_in,
                              void* d_out, int out_size, void* d_ws, size_t ws_size,
                              hipStream_t stream) {
    const float* x    = (const float*)d_in[0];   // [B, In, Din]
    const float* W    = (const float*)d_in[1];   // [N, C, Dout, Din]
    const float* bias = (const float*)d_in[2];   // [N, Dout]
    float* out = (float*)d_out;                  // [B, N, Dout]

    float* ws  = (float*)d_ws;
    float* s1  = ws;                                       // B*C*N*Dout = 1,048,576 f
    float* s2  = s1  + (size_t)B_ * C_ * N_ * Dout_;       // 1,048,576 f
    float* U_g = s2  + (size_t)B_ * C_ * N_ * Dout_;       // B*C*N*Din = 524,288 f
    float* v0  = U_g + (size_t)B_ * C_ * N_ * Din_;        // B*N*Dout  = 32,768 f

    caps_pre  <<<B_,      256, 0, stream>>>(x, W, bias, v0);
    caps_route<<<B_ * C_, 256, 0, stream>>>(x, W, bias, v0, nullptr, U_g, s1, 0);
    caps_route<<<B_ * C_, 256, 0, stream>>>(x, W, bias, nullptr, s1, U_g, s2, 1);
    caps_out  <<<B_,      256, 0, stream>>>(s2, bias, out);
}

// Round 6
// 90.563 us; speedup vs baseline: 2.0033x; 1.1943x over previous
//
#include <hip/hip_runtime.h>
#include <math.h>

constexpr int B_    = 32;
constexpr int In_   = 2048;
constexpr int Din_  = 8;
constexpr int N_    = 64;
constexpr int Dout_ = 16;
constexpr int C_    = 32;
constexpr int ICP   = 64;     // In_/C_
constexpr float EPS = 1e-7f;

// ---------------------------------------------------------------------------
// K1: v0 = squash(sum_c W[n,c,:,:].xbar[c,:] + bias). 8 blocks per b, each
// covers 8 n. xbar computed redundantly per block (cheap: 64 adds/thread).
// ---------------------------------------------------------------------------
__global__ __launch_bounds__(256) void caps_v0(
    const float* __restrict__ x, const float* __restrict__ W,
    const float* __restrict__ bias, float* __restrict__ v0)
{
    const int b = blockIdx.x >> 3, j = blockIdx.x & 7;
    const int t = threadIdx.x;

    __shared__ float xbar[C_][Din_];

    // phase 1: thread (c,k) sums its channel's 64 capsules
    {
        const int c = t >> 3, k = t & 7;
        const float* xp = x + (size_t)b * In_ * Din_ + (size_t)c * ICP * Din_ + k;
        float acc = 0.f;
        #pragma unroll 8
        for (int i = 0; i < ICP; ++i) acc += xp[i * Din_];
        xbar[c][k] = acc * (1.f / 64.f);
    }
    __syncthreads();

    // phase 2: lanes (nl = t>>5, d = (t&31)>>1, h = t&1); n = 8j+nl
    {
        const int nl = t >> 5, lane32 = t & 31;
        const int d = lane32 >> 1, h = lane32 & 1;
        const int n = j * 8 + nl;

        float a = 0.f;
        #pragma unroll
        for (int cc = 0; cc < 16; ++cc) {
            const int c2 = cc * 2 + h;
            const float4* wp = (const float4*)(W + (((size_t)n * C_ + c2) * Dout_ + d) * Din_);
            const float4 w0 = wp[0], w1 = wp[1];
            a += w0.x * xbar[c2][0] + w0.y * xbar[c2][1] + w0.z * xbar[c2][2] + w0.w * xbar[c2][3]
               + w1.x * xbar[c2][4] + w1.y * xbar[c2][5] + w1.z * xbar[c2][6] + w1.w * xbar[c2][7];
        }
        a += __shfl_xor(a, 1);              // both h-lanes: full sum over c
        a += bias[n * Dout_ + d];

        float sn = a * a;
        sn += __shfl_xor(sn, 2);
        sn += __shfl_xor(sn, 4);
        sn += __shfl_xor(sn, 8);
        sn += __shfl_xor(sn, 16);           // sum over the 16 d (same-h lanes)
        const float sc = sn / (1.f + sn) / sqrtf(sn + EPS);
        if (h == 0) v0[(size_t)b * 1024 + n * Dout_ + d] = a * sc;
    }
}

// ---------------------------------------------------------------------------
// Routing iteration: 256 threads per (b,c). v_src is the ALREADY-ACCUMULATED
// routing vector (v0 for iter1, v0+v1 for iter2 — U is linear in v, so no
// U accumulator buffer is needed). Writes s_out[b][c][n][d].
// ---------------------------------------------------------------------------
__global__ __launch_bounds__(256) void caps_route(
    const float* __restrict__ x, const float* __restrict__ W,
    const float* __restrict__ v_src, float* __restrict__ s_out)
{
    const int b = blockIdx.x >> 5;
    const int c = blockIdx.x & 31;
    const int t = threadIdx.x;
    const int w = t >> 6, l = t & 63;
    const int n4 = t >> 2, q4 = t & 3;

    __shared__ float Us[N_][8];            // 2 KB
    __shared__ float xs[ICP][8];           // 2 KB
    __shared__ float lg[ICP][68];          // 17 KB (b128-aligned rows)
    __shared__ float ps[4][ICP];           // 1 KB
    __shared__ float inv_s[ICP];
    __shared__ float ys[4][N_][8];         // 8 KB

    // ---- U stage: thread (n4,q4) covers d in [4q4,4q4+4); quad-shfl -> k pair
    {
        const float4 vv = *(const float4*)(v_src + ((size_t)b * 64 + n4) * 16 + q4 * 4);
        const float vd[4] = {vv.x, vv.y, vv.z, vv.w};
        float pU[8] = {0, 0, 0, 0, 0, 0, 0, 0};
        #pragma unroll
        for (int dd = 0; dd < 4; ++dd) {
            const int d = q4 * 4 + dd;
            const float4* wp = (const float4*)(W + (((size_t)n4 * 32 + c) * 16 + d) * 8);
            const float4 w0 = wp[0], w1 = wp[1];
            const float v_ = vd[dd];
            pU[0] += v_ * w0.x; pU[1] += v_ * w0.y; pU[2] += v_ * w0.z; pU[3] += v_ * w0.w;
            pU[4] += v_ * w1.x; pU[5] += v_ * w1.y; pU[6] += v_ * w1.z; pU[7] += v_ * w1.w;
        }
        #pragma unroll
        for (int k = 0; k < 8; ++k) {
            pU[k] += __shfl_xor(pU[k], 1);
            pU[k] += __shfl_xor(pU[k], 2);
        }
        float2 u2; u2.x = pU[2 * q4]; u2.y = pU[2 * q4 + 1];
        *(float2*)&Us[n4][2 * q4] = u2;
    }

    // ---- x fragment for lane's capsule i = l; wave 0 mirrors to LDS
    float xr[8];
    {
        const float4* xp = (const float4*)(x + ((size_t)b * In_ + c * ICP + l) * 8);
        const float4 x0 = xp[0], x1 = xp[1];
        xr[0] = x0.x; xr[1] = x0.y; xr[2] = x0.z; xr[3] = x0.w;
        xr[4] = x1.x; xr[5] = x1.y; xr[6] = x1.z; xr[7] = x1.w;
        if (w == 0) { *(float4*)&xs[l][0] = x0; *(float4*)&xs[l][4] = x1; }
    }
    __syncthreads();

    // ---- logits+exp: wave w covers n in [16w,16w+16); lane = i; Us broadcast
    {
        float e[16];
        float ssum = 0.f;
        #pragma unroll
        for (int nn = 0; nn < 16; ++nn) {
            const int n = w * 16 + nn;
            const float4 u0 = *(const float4*)&Us[n][0];
            const float4 u1 = *(const float4*)&Us[n][4];
            const float a = u0.x * xr[0] + u0.y * xr[1] + u0.z * xr[2] + u0.w * xr[3]
                          + u1.x * xr[4] + u1.y * xr[5] + u1.z * xr[6] + u1.w * xr[7];
            const float ee = __expf(a);    // no max-pass: logits bounded (validated R3-R5)
            e[nn] = ee; ssum += ee;
        }
        #pragma unroll
        for (int qq = 0; qq < 4; ++qq) {
            float4 o;
            o.x = e[qq * 4 + 0]; o.y = e[qq * 4 + 1]; o.z = e[qq * 4 + 2]; o.w = e[qq * 4 + 3];
            *(float4*)&lg[l][w * 16 + qq * 4] = o;
        }
        ps[w][l] = ssum;
    }
    __syncthreads();

    if (t < 64) inv_s[t] = 1.f / (ps[0][t] + ps[1][t] + ps[2][t] + ps[3][t]);
    __syncthreads();

    // ---- y stage: wave w covers i in [16w,16w+16); lane = (nq=l>>2, kq=l&3)
    {
        const int nq = l >> 2, kq = l & 3;
        float y[8] = {0, 0, 0, 0, 0, 0, 0, 0};
        #pragma unroll
        for (int ii = 0; ii < 16; ++ii) {
            const int i = w * 16 + ii;
            const float4 cw = *(const float4*)&lg[i][nq * 4];
            const float iv = inv_s[i];
            const float2 x2 = *(const float2*)&xs[i][kq * 2];
            const float c0 = cw.x * iv, c1 = cw.y * iv, c2 = cw.z * iv, c3 = cw.w * iv;
            y[0] += c0 * x2.x; y[1] += c0 * x2.y;
            y[2] += c1 * x2.x; y[3] += c1 * x2.y;
            y[4] += c2 * x2.x; y[5] += c2 * x2.y;
            y[6] += c3 * x2.x; y[7] += c3 * x2.y;
        }
        #pragma unroll
        for (int jj = 0; jj < 4; ++jj) {
            float2 o; o.x = y[2 * jj]; o.y = y[2 * jj + 1];
            *(float2*)&ys[w][nq * 4 + jj][kq * 2] = o;
        }
    }
    __syncthreads();

    // ---- s stage: thread (n4,q4): s_out[b][c][n][4q4..] = W[n,c,d,:].y[n,:]
    {
        float yn[8];
        #pragma unroll
        for (int k = 0; k < 8; ++k)
            yn[k] = ys[0][n4][k] + ys[1][n4][k] + ys[2][n4][k] + ys[3][n4][k];
        float4 o;
        float* op = (float*)&o;
        #pragma unroll
        for (int dd = 0; dd < 4; ++dd) {
            const int d = q4 * 4 + dd;
            const float4* wp = (const float4*)(W + (((size_t)n4 * 32 + c) * 16 + d) * 8);
            const float4 w0 = wp[0], w1 = wp[1];
            op[dd] = w0.x * yn[0] + w0.y * yn[1] + w0.z * yn[2] + w0.w * yn[3]
                   + w1.x * yn[4] + w1.y * yn[5] + w1.z * yn[6] + w1.w * yn[7];
        }
        *(float4*)(s_out + (((size_t)b * 32 + c) * 64 + n4) * 16 + q4 * 4) = o;
    }
}

// ---------------------------------------------------------------------------
// Reduce s over c + bias + squash -> dst; optionally dst += vadd (to build
// the accumulated v0+v1 for the next route's U). 8 blocks per b.
// ---------------------------------------------------------------------------
__global__ __launch_bounds__(256) void caps_reduce(
    const float* __restrict__ s_src, const float* __restrict__ bias,
    const float* __restrict__ vadd, float* __restrict__ dst)
{
    const int b = blockIdx.x >> 3, j = blockIdx.x & 7;
    const int t = threadIdx.x;
    const int nl = t >> 5, lane32 = t & 31;
    const int d = lane32 >> 1, h = lane32 & 1;
    const int n = j * 8 + nl;

    float a = 0.f;
    #pragma unroll
    for (int cc = 0; cc < 16; ++cc) {
        const int c2 = cc * 2 + h;
        a += s_src[(((size_t)b * 32 + c2) * 64 + n) * 16 + d];
    }
    a += __shfl_xor(a, 1);
    a += bias[n * Dout_ + d];

    float sn = a * a;
    sn += __shfl_xor(sn, 2);
    sn += __shfl_xor(sn, 4);
    sn += __shfl_xor(sn, 8);
    sn += __shfl_xor(sn, 16);
    const float sc = sn / (1.f + sn) / sqrtf(sn + EPS);
    float val = a * sc;
    if (vadd) val += vadd[(size_t)b * 1024 + n * Dout_ + d];
    if (h == 0) dst[(size_t)b * 1024 + n * Dout_ + d] = val;
}

extern "C" void kernel_launch(void* const* d_in, const int* in_sizes, int n_in,
                              void* d_out, int out_size, void* d_ws, size_t ws_size,
                              hipStream_t stream) {
    const float* x    = (const float*)d_in[0];   // [B, In, Din]
    const float* W    = (const float*)d_in[1];   // [N, C, Dout, Din]
    const float* bias = (const float*)d_in[2];   // [N, Dout]
    float* out = (float*)d_out;                  // [B, N, Dout]

    float* ws   = (float*)d_ws;
    float* s1   = ws;                                   // B*C*N*Dout = 1,048,576 f
    float* s2   = s1   + (size_t)B_ * C_ * N_ * Dout_;  // 1,048,576 f
    float* v0   = s2   + (size_t)B_ * C_ * N_ * Dout_;  // B*N*Dout = 32,768 f
    float* vsum = v0   + (size_t)B_ * N_ * Dout_;       // 32,768 f

    caps_v0    <<<256,  256, 0, stream>>>(x, W, bias, v0);
    caps_route <<<1024, 256, 0, stream>>>(x, W, v0, s1);
    caps_reduce<<<256,  256, 0, stream>>>(s1, bias, v0, vsum);    // vsum = v0 + v1
    caps_route <<<1024, 256, 0, stream>>>(x, W, vsum, s2);
    caps_reduce<<<256,  256, 0, stream>>>(s2, bias, nullptr, out);
}